// Round 9
// baseline (296.585 us; speedup 1.0000x reference)
//
#include <hip/hip_runtime.h>
#include <stdint.h>

#define HIDDEN 1024
#define HEADS 16
#define HEAD_DIM 64
#define BATCH 4
#define SEQ 2048
#define NTOK (BATCH * SEQ)   // 8192

typedef __attribute__((ext_vector_type(8))) short bf16x8;
typedef __attribute__((ext_vector_type(4))) float floatx4;
typedef __attribute__((ext_vector_type(16))) float floatx16;

// log2(e) / sqrt(HEAD_DIM) : folded into Q so p = exp2(s) directly
#define SCALE_Q 0.18033688011112042f

__device__ __forceinline__ unsigned short f2bf(float f) {
    union { float f; unsigned u; } x; x.f = f;
    unsigned r = x.u + 0x7fffu + ((x.u >> 16) & 1u);
    return (unsigned short)(r >> 16);
}

__device__ __forceinline__ float fast_exp2(float x) {
#if __has_builtin(__builtin_amdgcn_exp2f)
    return __builtin_amdgcn_exp2f(x);
#else
    return exp2f(x);
#endif
}

typedef __attribute__((address_space(3))) unsigned int lds_u32;
typedef const __attribute__((address_space(1))) unsigned int gl_u32;

// async global->LDS, 16B per lane; l is the WAVE-UNIFORM base (HW scatters
// lane i's 16B to l + i*16).
__device__ __forceinline__ void async_cp16(const void* g, void* l) {
#if __has_builtin(__builtin_amdgcn_global_load_lds)
    __builtin_amdgcn_global_load_lds((gl_u32*)g, (lds_u32*)l, 16, 0, 0);
#else
    *(uint4*)((char*)l + (threadIdx.x & 63) * 16) = *(const uint4*)g;
#endif
}

// ---- fused fp32->bf16 conversion for x, Wq, Wk, Wv + zero of accp ----------
__global__ __launch_bounds__(256) void conv_all(
    const float* __restrict__ x, const float* __restrict__ Wq,
    const float* __restrict__ Wk, const float* __restrict__ Wv,
    unsigned short* __restrict__ x_bf, unsigned short* __restrict__ wq_bf,
    unsigned short* __restrict__ wk_bf, unsigned short* __restrict__ wv_bf,
    float* __restrict__ accp) {
    const int blk = blockIdx.x, tid = threadIdx.x;
    const float* src;
    unsigned short* dst;
    size_t i;
    if (blk < 8192) {
        src = x; dst = x_bf; i = (size_t)blk * 256 + tid;
        if (blk < 16) accp[blk * 256 + tid] = 0.0f;
    } else {
        int r = blk - 8192;
        int s = r >> 10;
        src = (s == 0) ? Wq : (s == 1) ? Wk : Wv;
        dst = (s == 0) ? wq_bf : (s == 1) ? wk_bf : wv_bf;
        i = (size_t)(r & 1023) * 256 + tid;
    }
    float4 v = *(const float4*)(src + 4 * i);
    unsigned short o[4];
    o[0] = f2bf(v.x); o[1] = f2bf(v.y); o[2] = f2bf(v.z); o[3] = f2bf(v.w);
    *(ushort4*)(dst + 4 * i) = *(ushort4*)o;
}

// ---- QKV GEMM, single N=3072 GEMM of 256x128 tiles -------------------------
// grid 768 = 24 nzb x 32 mb (XCD = mb%8; same-mb blocks share the 512KB X
// panel XCD-locally). Tile: 256x128, 4 waves x (128x64) -> 32 MFMAs per
// barrier interval. BK=32, 2-set LDS pipeline with counted vmcnt:
// STAGE(t+1) -> vmcnt(6) -> bar -> COMPUTE -> lgkmcnt(0) -> bar.
// OCCUPANCY FIX (r9): __launch_bounds__(256,3) -> 3 blocks/CU (48K LDS x 3 =
// 144K <= 160K, VGPR 96 <= 170). grid 768 = EXACTLY 3 x 256 CUs: ONE dispatch
// round, no tail (r8's (256,2) gave 512 slots -> 1.5 rounds, last round ran
// 1 block/CU on half the chip; occupancy 15%, dur flat at 79 us).
// Epilogue: TWO sequential 128-row transpose passes through tbuf (wave-parity
// gated), every global store 128 B contiguous per thread.
// z==0 (Q): scaled by SCALE_Q.  z==2 (V): transposed output Vt[bh*64+d][t]
// with key-granule PERMUTATION (swap bits 2,3 of key index) so the attention
// kernel's PV B-frag (keys {0-3,8-11}+4g2 of a 16-key step) is one b128.
__global__ __launch_bounds__(256, 3) void qkv_gemm(
    const unsigned short* __restrict__ X,
    const unsigned short* __restrict__ W0, const unsigned short* __restrict__ W1,
    const unsigned short* __restrict__ W2,
    const float* __restrict__ b0, const float* __restrict__ b1,
    const float* __restrict__ b2,
    unsigned short* __restrict__ O0, unsigned short* __restrict__ O1,
    unsigned short* __restrict__ O2) {
    // 2 sets x (A 16K | B 8K) = 48K; tbuf (34816 B) aliases set 0 + part of 1
    __shared__ __align__(16) char smem[49152];
    unsigned short* tbuf = (unsigned short*)smem;

    const int id = blockIdx.x;
    const int mb = id & 31, nzb = id >> 5;
    const int z = nzb >> 3, nz = nzb & 7;
    const int m0 = mb * 256;
    const unsigned short* W = (z == 0) ? W0 : (z == 1) ? W1 : W2;
    const float* bias       = (z == 0) ? b0 : (z == 1) ? b1 : b2;

    const int tid = threadIdx.x, lane = tid & 63, wave = tid >> 6;
    const int wmB = (wave & 1) * 128;        // wave m-offset (128-row half)
    const int wn  = (wave >> 1) * 64;        // wave n-offset

    // staging: wave w covers A rows [64w, 64w+64) (4 instr x 16 rows) and
    // B rows [32w, 32w+32) (2 instr). global column chunk = (l&3) ^ (row&3)
    // (XOR swizzle baked into the global address; LDS writes lane-linear).
    const int srow = lane >> 2;
    const int sxc = ((lane & 3) ^ (srow & 3)) * 8;   // shorts
    const unsigned short* ga[4];
    const unsigned short* gb[2];
#pragma unroll
    for (int j = 0; j < 4; ++j)
        ga[j] = X + (size_t)(m0 + wave * 64 + j * 16 + srow) * HIDDEN + sxc;
#pragma unroll
    for (int j = 0; j < 2; ++j)
        gb[j] = W + (size_t)(nz * 128 + wave * 32 + j * 16 + srow) * HIDDEN + sxc;

    floatx4 acc[8][4];
#pragma unroll
    for (int tm = 0; tm < 8; ++tm)
#pragma unroll
        for (int tn = 0; tn < 4; ++tn)
#pragma unroll
            for (int r = 0; r < 4; ++r) acc[tm][tn][r] = 0.f;

    // stage tile into LDS set s (6 gloads/wave; advances pointers by BK)
    auto STAGE = [&](int s) {
#pragma unroll
        for (int j = 0; j < 4; ++j) {
            async_cp16(ga[j], smem + s * 24576 + wave * 4096 + j * 1024);
            ga[j] += 32;
        }
#pragma unroll
        for (int j = 0; j < 2; ++j) {
            async_cp16(gb[j], smem + s * 24576 + 16384 + wave * 2048 + j * 1024);
            gb[j] += 32;
        }
    };
    // frag read: row*64 + (kc ^ (row&3))*16 ; row%4 == lane%4 for all frags
    const int fr = (lane & 15) * 64 + (((lane >> 4) ^ (lane & 3)) * 16);
    auto COMPUTE = [&](int s) {
        const char* Ab = smem + s * 24576;
        const char* Bb = Ab + 16384;
        bf16x8 af[8], bfr[4];
#pragma unroll
        for (int t = 0; t < 8; ++t)
            af[t]  = *(bf16x8*)(Ab + (wmB + t * 16) * 64 + fr);
#pragma unroll
        for (int t = 0; t < 4; ++t)
            bfr[t] = *(bf16x8*)(Bb + (wn + t * 16) * 64 + fr);
        __builtin_amdgcn_s_setprio(1);
#pragma unroll
        for (int tm = 0; tm < 8; ++tm)
#pragma unroll
            for (int tn = 0; tn < 4; ++tn)
                acc[tm][tn] = __builtin_amdgcn_mfma_f32_16x16x32_bf16(af[tm], bfr[tn], acc[tm][tn], 0, 0, 0);
        __builtin_amdgcn_s_setprio(0);
    };

    // prologue: tile 0 into set 0 (6 loads in flight; no wait yet)
    STAGE(0);

    int cur = 0;
    for (int kt = 0; kt < 31; ++kt) {
        STAGE(cur ^ 1);                          // tile kt+1
        asm volatile("s_waitcnt vmcnt(6)" ::: "memory");   // tile kt landed
        __builtin_amdgcn_sched_barrier(0);
        asm volatile("s_barrier" ::: "memory");
        __builtin_amdgcn_sched_barrier(0);
        COMPUTE(cur);
        asm volatile("s_waitcnt lgkmcnt(0)" ::: "memory"); // my reads done
        __builtin_amdgcn_sched_barrier(0);
        asm volatile("s_barrier" ::: "memory");  // all reads done; set may be overwritten
        __builtin_amdgcn_sched_barrier(0);
        cur ^= 1;
    }
    // kt = 31: last tile already staged
    asm volatile("s_waitcnt vmcnt(0)" ::: "memory");
    __builtin_amdgcn_sched_barrier(0);
    asm volatile("s_barrier" ::: "memory");
    __builtin_amdgcn_sched_barrier(0);
    COMPUTE(cur);

    // ---- epilogue: two 128-row passes via LDS transpose (tbuf aliases) -----
    // C/D map: col = lane&15, row = (lane>>4)*4 + reg. Pass p handles block
    // rows [128p, 128p+128): written by waves with (wave&1)==p (their wmB).
    const int col = lane & 15, rbase = (lane >> 4) * 4;
    __syncthreads();   // all frag reads done before tbuf overwrites sets
#pragma unroll
    for (int p = 0; p < 2; ++p) {
        if ((wave & 1) == p) {
            if (z == 2) {
                // V: tbuf [d 0..127][tok 0..127], row stride 136 shorts.
                // Key-granule permutation: swap bits 2,3 of local token idx.
#pragma unroll
                for (int tm = 0; tm < 8; ++tm)
#pragma unroll
                    for (int tn = 0; tn < 4; ++tn) {
                        const int dr = wn + tn * 16 + col;      // 0..127
                        const float bs = bias[nz * 128 + dr];
                        const int mi0 = tm * 16 + rbase;        // 0..127 local
                        const int mip = (mi0 & ~12) | ((mi0 & 4) << 1) | ((mi0 & 8) >> 1);
                        unsigned short vals[4];
#pragma unroll
                        for (int r = 0; r < 4; ++r) vals[r] = f2bf(acc[tm][tn][r] + bs);
                        *(ushort4*)&tbuf[dr * 136 + mip] = *(ushort4*)vals;
                    }
            } else {
                const float sc = (z == 0) ? SCALE_Q : 1.0f;
                // Q/K: tbuf [tok 0..127][n 0..127], row stride 136 shorts
#pragma unroll
                for (int tm = 0; tm < 8; ++tm)
#pragma unroll
                    for (int tn = 0; tn < 4; ++tn) {
                        const int nn = wn + tn * 16 + col;      // 0..127
                        const float bs = bias[nz * 128 + nn];
                        const int mi0 = tm * 16 + rbase;        // 0..127 local
#pragma unroll
                        for (int r = 0; r < 4; ++r)
                            tbuf[(mi0 + r) * 136 + nn] = f2bf((acc[tm][tn][r] + bs) * sc);
                    }
            }
        }
        __syncthreads();
        // writeback: each thread one 128 B contiguous chunk
        if (z == 2) {
            const int dr = tid >> 1, seg = tid & 1;
            const int hh = nz * 2 + (dr >> 6), dd = dr & 63;
            const int mrow = m0 + p * 128;
            const int bb = mrow >> 11, tb = (mrow & (SEQ - 1)) >> 7;
            unsigned short* dst = O2 + (((size_t)bb * HEADS + hh) * HEAD_DIM + dd) * SEQ
                                     + tb * 128 + seg * 64;
            const unsigned short* srcl = &tbuf[dr * 136 + seg * 64];
#pragma unroll
            for (int i = 0; i < 8; ++i)
                *(uint4*)(dst + i * 8) = *(const uint4*)(srcl + i * 8);
        } else {
            unsigned short* O = (z == 0) ? O0 : O1;
            const int r = tid >> 1, seg = tid & 1;
            unsigned short* dst = O + (size_t)(m0 + p * 128 + r) * HIDDEN + nz * 128 + seg * 64;
            const unsigned short* srcl = &tbuf[r * 136 + seg * 64];
#pragma unroll
            for (int i = 0; i < 8; ++i)
                *(uint4*)(dst + i * 8) = *(const uint4*)(srcl + i * 8);
        }
        __syncthreads();   // tbuf reads done before next pass overwrites
    }
}

// ---- MFMA flash attention: 128 q/block, 2 waves, 64-key dbuf, 4 blk/CU -----
// grid 1024 (= 64 bh x 16 qc). XCD swizzle: all 16 q-chunks of one (b,h) on
// one XCD. TWO q-groups of 32 per wave (64 q/wave): K/V LDS frags read ONCE
// feed BOTH groups (16 ds_read : 32 MFMA per wave-iter). 2-wave blocks give
// 4 INDEPENDENT blocks/CU -> each SIMD's 2 waves come from different blocks
// (decorrelated phases; one wave's MFMAs cover the other's softmax VALU).
// Issue order per s32: all 8 QK MFMAs -> V-frag ds_reads -> exp/pack (VALU,
// overlaps QK execution) -> all 8 PV MFMAs. No setprio (lockstep-null).
// l accumulated on the VALU; epilogue redistributes per-query-row via shfl.
__global__ __launch_bounds__(128, 2) void attn_mfma(
    const unsigned short* __restrict__ Q, const unsigned short* __restrict__ K,
    const unsigned short* __restrict__ Vt, float* __restrict__ accp) {
    __shared__ unsigned short Klds[2][4096];  // 64 keys x 64 d, chunk-swizzled
    __shared__ unsigned short Vlds[2][4096];  // 64 d x 64 keys (perm), swizzled

    const int tid = threadIdx.x, lane = tid & 63, wave = tid >> 6;  // wave 0..1
    const int lq = lane & 31, g2 = lane >> 5;

    const int f = blockIdx.x;                 // 1024 = 64 bh x 16 qc
    const int bh = (f & 7) * 8 + ((f >> 3) & 7);
    const int qc = f >> 6;                    // 0..15 (128-q chunk)
    const int b = bh >> 4, h = bh & 15;

    // Q B-fragments: 2 groups of 32 q per wave, 4 k-slices each
    bf16x8 qfrag[2][4];
#pragma unroll
    for (int grp = 0; grp < 2; ++grp) {
        const size_t qb = ((size_t)(b * SEQ + qc * 128 + wave * 64 + grp * 32 + lq)) * HIDDEN
                          + h * HEAD_DIM + g2 * 8;
#pragma unroll
        for (int ds = 0; ds < 4; ++ds) qfrag[grp][ds] = *(const bf16x8*)&Q[qb + ds * 16];
    }

    // staging pointers. K: wave w covers rows [32w,32w+32) (4 instr x 8 rows);
    // V: d-rows [32w,32w+32). XOR chunk swizzle baked into the GLOBAL address
    // so lane-linear LDS writes give the swizzled layout.
    const unsigned short* kg[4];
    const unsigned short* vg[4];
    {
        const int kr = lane >> 3;                       // 0..7
        const int kc = ((lane & 7) ^ kr) * 8;
#pragma unroll
        for (int j = 0; j < 4; ++j)
            kg[j] = K + ((size_t)(b * SEQ + wave * 32 + j * 8 + kr)) * HIDDEN + h * HEAD_DIM + kc;
#pragma unroll
        for (int j = 0; j < 4; ++j) {
            const int dl = wave * 32 + j * 8 + (lane >> 3);
            const int cc = ((lane & 7) ^ (dl & 7)) * 8;
            vg[j] = Vt + ((size_t)bh * HEAD_DIM + dl) * SEQ + cc;
        }
    }

    floatx16 oacc[2][2];                      // [grp][nf]
#pragma unroll
    for (int r = 0; r < 16; ++r) {
        oacc[0][0][r] = 0.f; oacc[0][1][r] = 0.f;
        oacc[1][0][r] = 0.f; oacc[1][1][r] = 0.f;
    }
    // softmax denominator partials per group (two chains each)
    float lsum00 = 0.f, lsum01 = 0.f, lsum10 = 0.f, lsum11 = 0.f;

    // prologue: stage tile 0 into buf 0
#pragma unroll
    for (int j = 0; j < 4; ++j) {
        async_cp16(kg[j], (char*)Klds[0] + (wave * 32 + j * 8) * 128);
        async_cp16(vg[j], (char*)Vlds[0] + (wave * 32 + j * 8) * 128);
        kg[j] += 64 * HIDDEN; vg[j] += 64;
    }
    __syncthreads();

    for (int it = 0; it < 32; ++it) {
        const int cur = it & 1;
        if (it < 31) {
#pragma unroll
            for (int j = 0; j < 4; ++j) {
                async_cp16(kg[j], (char*)Klds[cur ^ 1] + (wave * 32 + j * 8) * 128);
                async_cp16(vg[j], (char*)Vlds[cur ^ 1] + (wave * 32 + j * 8) * 128);
                kg[j] += 64 * HIDDEN; vg[j] += 64;
            }
        }
#pragma unroll
        for (int s32 = 0; s32 < 2; ++s32) {
            const int rr = s32 * 32 + lq;
            bf16x8 kf[4];
#pragma unroll
            for (int ds = 0; ds < 4; ++ds)
                kf[ds] = *(bf16x8*)((char*)Klds[cur] + rr * 128 + (((g2 + 2 * ds) ^ (lq & 7)) * 16));

            // --- all QK^T MFMAs first (two independent chains) ---
            floatx16 sacc0, sacc1;
#pragma unroll
            for (int r = 0; r < 16; ++r) { sacc0[r] = 0.f; sacc1[r] = 0.f; }
#pragma unroll
            for (int ds = 0; ds < 4; ++ds)
                sacc0 = __builtin_amdgcn_mfma_f32_32x32x16_bf16(kf[ds], qfrag[0][ds], sacc0, 0, 0, 0);
#pragma unroll
            for (int ds = 0; ds < 4; ++ds)
                sacc1 = __builtin_amdgcn_mfma_f32_32x32x16_bf16(kf[ds], qfrag[1][ds], sacc1, 0, 0, 0);

            // --- V-frag ds_reads issued early: latency hides under exp2 ---
            bf16x8 vf[2][2];                 // [ks2][nf]
#pragma unroll
            for (int ks2 = 0; ks2 < 2; ++ks2)
#pragma unroll
                for (int nf = 0; nf < 2; ++nf) {
                    const int d = nf * 32 + lq;
                    const int c = (2 * (s32 * 2 + ks2) + g2) ^ (d & 7);
                    vf[ks2][nf] = *(bf16x8*)((char*)Vlds[cur] + d * 128 + c * 16);
                }

            // --- softmax exp/pack for both groups (overlaps QK execution) ---
            unsigned pk[2][8];
#pragma unroll
            for (int j = 0; j < 8; ++j) {
                union { float f; unsigned u; } plo, phi;
                plo.f = fast_exp2(sacc0[2 * j]);
                phi.f = fast_exp2(sacc0[2 * j + 1]);
                lsum00 += plo.f; lsum01 += phi.f;
                pk[0][j] = __builtin_amdgcn_perm(phi.u, plo.u, 0x07060302u);
            }
#pragma unroll
            for (int j = 0; j < 8; ++j) {
                union { float f; unsigned u; } plo, phi;
                plo.f = fast_exp2(sacc1[2 * j]);
                phi.f = fast_exp2(sacc1[2 * j + 1]);
                lsum10 += plo.f; lsum11 += phi.f;
                pk[1][j] = __builtin_amdgcn_perm(phi.u, plo.u, 0x07060302u);
            }

            // --- all PV MFMAs ---
#pragma unroll
            for (int ks2 = 0; ks2 < 2; ++ks2)
#pragma unroll
                for (int grp = 0; grp < 2; ++grp) {
                    union { uint4 u; bf16x8 v; } af;
                    af.u.x = pk[grp][4 * ks2];
                    af.u.y = pk[grp][4 * ks2 + 1];
                    af.u.z = pk[grp][4 * ks2 + 2];
                    af.u.w = pk[grp][4 * ks2 + 3];
#pragma unroll
                    for (int nf = 0; nf < 2; ++nf)
                        oacc[grp][nf] = __builtin_amdgcn_mfma_f32_32x32x16_bf16(af.v, vf[ks2][nf], oacc[grp][nf], 0, 0, 0);
                }
        }
        if (it < 31) __syncthreads();
    }

    // epilogue: per group, combine l partials (per query column lq) across the
    // two g2 halves, then redistribute to this lane's 16 oacc query ROWS:
    // q_r = (r&3) + 8*(r>>2) + 4*g2 ; l[q] lives in lanes q and q+32.
    float linv[2][16];
#pragma unroll
    for (int grp = 0; grp < 2; ++grp) {
        float lf = (grp == 0) ? (lsum00 + lsum01) : (lsum10 + lsum11);
        lf += __shfl_xor(lf, 32, 64);
#pragma unroll
        for (int r = 0; r < 16; ++r) {
            const int qr = (r & 3) + 8 * (r >> 2) + 4 * g2;
            linv[grp][r] = 1.0f / __shfl(lf, qr, 64);
        }
    }
    // d-col = lane&31 (+32*nf); sum_q o[q][d]/l[q] over the wave's 64 rows
#pragma unroll
    for (int nf = 0; nf < 2; ++nf) {
        float v = 0.f;
#pragma unroll
        for (int r = 0; r < 16; ++r)
            v += oacc[0][nf][r] * linv[0][r] + oacc[1][nf][r] * linv[1][r];
        v += __shfl_xor(v, 32, 64);
        if (lane < 32)
            atomicAdd(&accp[b * HIDDEN + h * HEAD_DIM + nf * 32 + lq], v);
    }
}

// ---- final projection: out = (acc/T) @ Wo^T + bo ---------------------------
// grid 256: block bi covers n = 4*bi..4*bi+3, ALL 4 batches (full-chip).
// 64 lanes per n, each lane 16 k-elements; wave shuffle-reduce; lanes 0-3
// write the 4 batch outputs.
__global__ __launch_bounds__(256) void out_proj(const float* __restrict__ acc,
                                                const float* __restrict__ Wo,
                                                const float* __restrict__ bo,
                                                float* __restrict__ out) {
    const int tid = threadIdx.x;
    const int nl = tid >> 6, lane = tid & 63;
    const int n = blockIdx.x * 4 + nl;
    const float* wr = Wo + (size_t)n * HIDDEN + lane * 16;
    float s0 = 0.f, s1 = 0.f, s2 = 0.f, s3 = 0.f;
#pragma unroll
    for (int kk = 0; kk < 4; ++kk) {
        float4 w = *(const float4*)(wr + kk * 4);
        float4 a0 = *(const float4*)(acc + 0 * HIDDEN + lane * 16 + kk * 4);
        float4 a1 = *(const float4*)(acc + 1 * HIDDEN + lane * 16 + kk * 4);
        float4 a2 = *(const float4*)(acc + 2 * HIDDEN + lane * 16 + kk * 4);
        float4 a3 = *(const float4*)(acc + 3 * HIDDEN + lane * 16 + kk * 4);
        s0 += w.x * a0.x + w.y * a0.y + w.z * a0.z + w.w * a0.w;
        s1 += w.x * a1.x + w.y * a1.y + w.z * a1.z + w.w * a1.w;
        s2 += w.x * a2.x + w.y * a2.y + w.z * a2.z + w.w * a2.w;
        s3 += w.x * a3.x + w.y * a3.y + w.z * a3.z + w.w * a3.w;
    }
#pragma unroll
    for (int off = 32; off; off >>= 1) {
        s0 += __shfl_xor(s0, off, 64);
        s1 += __shfl_xor(s1, off, 64);
        s2 += __shfl_xor(s2, off, 64);
        s3 += __shfl_xor(s3, off, 64);
    }
    if (lane < 4) {
        float sv = (lane == 0) ? s0 : (lane == 1) ? s1 : (lane == 2) ? s2 : s3;
        out[lane * HIDDEN + n] = sv * (1.0f / (float)SEQ) + bo[n];
    }
}

extern "C" void kernel_launch(void* const* d_in, const int* in_sizes, int n_in,
                              void* d_out, int out_size, void* d_ws, size_t ws_size,
                              hipStream_t stream) {
    const float* x  = (const float*)d_in[0];
    const float* Wq = (const float*)d_in[1];
    const float* bq = (const float*)d_in[2];
    const float* Wk = (const float*)d_in[3];
    const float* bk = (const float*)d_in[4];
    const float* Wv = (const float*)d_in[5];
    const float* bv = (const float*)d_in[6];
    const float* Wo = (const float*)d_in[7];
    const float* bo = (const float*)d_in[8];
    float* out = (float*)d_out;

    char* ws = (char*)d_ws;
    unsigned short* x_bf  = (unsigned short*)(ws);                      // 16 MB
    unsigned short* wq_bf = (unsigned short*)(ws + 16777216);           //  2 MB
    unsigned short* wk_bf = (unsigned short*)(ws + 18874368);           //  2 MB
    unsigned short* wv_bf = (unsigned short*)(ws + 20971520);           //  2 MB
    unsigned short* q_bf  = (unsigned short*)(ws + 23068672);           // 16 MB (pre-scaled Q)
    unsigned short* k_bf  = (unsigned short*)(ws + 39845888);           // 16 MB
    unsigned short* vt_bf = (unsigned short*)(ws + 56623104);           // 16 MB (V^T, granule-perm)
    float*          accp  = (float*)(ws + 73400320);                    // 16 KB

    conv_all<<<dim3(8192 + 3072), dim3(256), 0, stream>>>(
        x, Wq, Wk, Wv, x_bf, wq_bf, wk_bf, wv_bf, accp);

    qkv_gemm<<<dim3(768), dim3(256), 0, stream>>>(
        x_bf, wq_bf, wk_bf, wv_bf, bq, bk, bv, q_bf, k_bf, vt_bf);

    attn_mfma<<<dim3(1024), dim3(128), 0, stream>>>(q_bf, k_bf, vt_bf, accp);

    out_proj<<<dim3(256), dim3(256), 0, stream>>>(accp, Wo, bo, out);
}

// Round 10
// 233.868 us; speedup vs baseline: 1.2682x; 1.2682x over previous
//
#include <hip/hip_runtime.h>
#include <stdint.h>

#define HIDDEN 1024
#define HEADS 16
#define HEAD_DIM 64
#define BATCH 4
#define SEQ 2048
#define NTOK (BATCH * SEQ)   // 8192

typedef __attribute__((ext_vector_type(8))) short bf16x8;
typedef __attribute__((ext_vector_type(4))) float floatx4;
typedef __attribute__((ext_vector_type(16))) float floatx16;

// log2(e) / sqrt(HEAD_DIM) : folded into Q so p = exp2(s) directly
#define SCALE_Q 0.18033688011112042f

__device__ __forceinline__ unsigned short f2bf(float f) {
    union { float f; unsigned u; } x; x.f = f;
    unsigned r = x.u + 0x7fffu + ((x.u >> 16) & 1u);
    return (unsigned short)(r >> 16);
}

__device__ __forceinline__ float fast_exp2(float x) {
#if __has_builtin(__builtin_amdgcn_exp2f)
    return __builtin_amdgcn_exp2f(x);
#else
    return exp2f(x);
#endif
}

typedef __attribute__((address_space(3))) unsigned int lds_u32;
typedef const __attribute__((address_space(1))) unsigned int gl_u32;

// async global->LDS, 16B per lane; l is the WAVE-UNIFORM base (HW scatters
// lane i's 16B to l + i*16).
__device__ __forceinline__ void async_cp16(const void* g, void* l) {
#if __has_builtin(__builtin_amdgcn_global_load_lds)
    __builtin_amdgcn_global_load_lds((gl_u32*)g, (lds_u32*)l, 16, 0, 0);
#else
    *(uint4*)((char*)l + (threadIdx.x & 63) * 16) = *(const uint4*)g;
#endif
}

// ---- fused fp32->bf16 conversion for x, Wq, Wk, Wv + zero of accp ----------
__global__ __launch_bounds__(256) void conv_all(
    const float* __restrict__ x, const float* __restrict__ Wq,
    const float* __restrict__ Wk, const float* __restrict__ Wv,
    unsigned short* __restrict__ x_bf, unsigned short* __restrict__ wq_bf,
    unsigned short* __restrict__ wk_bf, unsigned short* __restrict__ wv_bf,
    float* __restrict__ accp) {
    const int blk = blockIdx.x, tid = threadIdx.x;
    const float* src;
    unsigned short* dst;
    size_t i;
    if (blk < 8192) {
        src = x; dst = x_bf; i = (size_t)blk * 256 + tid;
        if (blk < 16) accp[blk * 256 + tid] = 0.0f;
    } else {
        int r = blk - 8192;
        int s = r >> 10;
        src = (s == 0) ? Wq : (s == 1) ? Wk : Wv;
        dst = (s == 0) ? wq_bf : (s == 1) ? wk_bf : wv_bf;
        i = (size_t)(r & 1023) * 256 + tid;
    }
    float4 v = *(const float4*)(src + 4 * i);
    unsigned short o[4];
    o[0] = f2bf(v.x); o[1] = f2bf(v.y); o[2] = f2bf(v.z); o[3] = f2bf(v.w);
    *(ushort4*)(dst + 4 * i) = *(ushort4*)o;
}

// ---- QKV GEMM, single N=3072 GEMM of 128x128 tiles (r7-measured version) ---
// grid 1536 = 24 nzb x 64 mb (XCD = mb%8). Tile: 128x128, 4 waves x (64x64),
// BK=32, THREE-buffer LDS pipeline with counted vmcnt. Measured r7: 80.5 us,
// VGPR 68 (+64 acc AGPR = 132 < 170 budget at 3 blocks/CU -> NO spill).
// r8/r9 fat-tile variants (256x128) regressed: 2 blk/CU -> dispatch tail
// (flat); 3 blk/CU -> acc spill to scratch (WRITE_SIZE 4x, qkv 141 us).
// Epilogue via LDS transpose buffer (aliases sets): every global store is
// 128 B contiguous per thread.
// z==0 (Q): scaled by SCALE_Q.  z==2 (V): transposed output Vt[bh*64+d][t]
// with key-granule PERMUTATION (swap bits 2,3 of key index) so the attention
// kernel's PV B-frag (keys {0-3,8-11}+4g2 of a 16-key step) is one b128.
__global__ __launch_bounds__(256, 3) void qkv_gemm(
    const unsigned short* __restrict__ X,
    const unsigned short* __restrict__ W0, const unsigned short* __restrict__ W1,
    const unsigned short* __restrict__ W2,
    const float* __restrict__ b0, const float* __restrict__ b1,
    const float* __restrict__ b2,
    unsigned short* __restrict__ O0, unsigned short* __restrict__ O1,
    unsigned short* __restrict__ O2) {
    // 3 sets x (A 8K | B 8K) = 48K; tbuf (34816 B) aliases sets 0-1
    __shared__ __align__(16) char smem[49152];
    unsigned short* tbuf = (unsigned short*)smem;

    const int id = blockIdx.x;
    const int mb = id & 63, nzb = id >> 6;
    const int z = nzb >> 3, nz = nzb & 7;
    const int m0 = mb * 128;
    const unsigned short* W = (z == 0) ? W0 : (z == 1) ? W1 : W2;
    const float* bias       = (z == 0) ? b0 : (z == 1) ? b1 : b2;

    const int tid = threadIdx.x, lane = tid & 63, wave = tid >> 6;
    const int wm = (wave & 1) * 64, wn = (wave >> 1) * 64;

    // staging: wave w covers rows [32w, 32w+32): 2 instrs x 16 rows.
    // global column chunk = (l&3) ^ (row&3)  (XOR swizzle baked in)
    const int srow = lane >> 2;
    const int sxc = ((lane & 3) ^ (srow & 3)) * 8;   // shorts
    const unsigned short* ga[2];
    const unsigned short* gb[2];
#pragma unroll
    for (int j = 0; j < 2; ++j) {
        ga[j] = X + (size_t)(m0 + wave * 32 + j * 16 + srow) * HIDDEN + sxc;
        gb[j] = W + (size_t)(nz * 128 + wave * 32 + j * 16 + srow) * HIDDEN + sxc;
    }

    floatx4 acc[4][4];
#pragma unroll
    for (int tm = 0; tm < 4; ++tm)
#pragma unroll
        for (int tn = 0; tn < 4; ++tn)
#pragma unroll
            for (int r = 0; r < 4; ++r) acc[tm][tn][r] = 0.f;

    // stage tile into LDS set s (4 gloads/wave; advances pointers by BK)
    auto STAGE = [&](int s) {
#pragma unroll
        for (int j = 0; j < 2; ++j) {
            async_cp16(ga[j], smem + s * 16384 + wave * 2048 + j * 1024);
            async_cp16(gb[j], smem + s * 16384 + 8192 + wave * 2048 + j * 1024);
            ga[j] += 32; gb[j] += 32;
        }
    };
    // frag read: row*64 + (kc ^ (row&3))*16 ; row%4 == lane%4 for all frags
    const int fr = (lane & 15) * 64 + (((lane >> 4) ^ (lane & 3)) * 16);
    auto COMPUTE = [&](int s) {
        const char* Ab = smem + s * 16384;
        const char* Bb = Ab + 8192;
        bf16x8 af[4], bfr[4];
#pragma unroll
        for (int t = 0; t < 4; ++t) {
            af[t]  = *(bf16x8*)(Ab + (wm + t * 16) * 64 + fr);
            bfr[t] = *(bf16x8*)(Bb + (wn + t * 16) * 64 + fr);
        }
        __builtin_amdgcn_s_setprio(1);
#pragma unroll
        for (int tm = 0; tm < 4; ++tm)
#pragma unroll
            for (int tn = 0; tn < 4; ++tn)
                acc[tm][tn] = __builtin_amdgcn_mfma_f32_16x16x32_bf16(af[tm], bfr[tn], acc[tm][tn], 0, 0, 0);
        __builtin_amdgcn_s_setprio(0);
    };

    // prologue: tiles 0,1 into sets 0,1 (8 loads in flight; no wait yet)
    STAGE(0);
    STAGE(1);

    int rs = 0, ss = 2;
    for (int kt = 0; kt < 30; ++kt) {
        STAGE(ss);                               // tile kt+2
        asm volatile("s_waitcnt vmcnt(8)" ::: "memory");   // tile kt landed
        __builtin_amdgcn_sched_barrier(0);
        asm volatile("s_barrier" ::: "memory");
        __builtin_amdgcn_sched_barrier(0);
        COMPUTE(rs);
        asm volatile("s_waitcnt lgkmcnt(0)" ::: "memory"); // my reads done
        __builtin_amdgcn_sched_barrier(0);
        asm volatile("s_barrier" ::: "memory");  // all reads done; set may be overwritten
        __builtin_amdgcn_sched_barrier(0);
        rs = (rs == 2) ? 0 : rs + 1;
        ss = (ss == 2) ? 0 : ss + 1;
    }
    // kt = 30: no stage; only tile 31's 4 loads may remain
    asm volatile("s_waitcnt vmcnt(4)" ::: "memory");
    __builtin_amdgcn_sched_barrier(0);
    asm volatile("s_barrier" ::: "memory");
    __builtin_amdgcn_sched_barrier(0);
    COMPUTE(rs);
    asm volatile("s_waitcnt lgkmcnt(0)" ::: "memory");
    __builtin_amdgcn_sched_barrier(0);
    asm volatile("s_barrier" ::: "memory");
    __builtin_amdgcn_sched_barrier(0);
    rs = (rs == 2) ? 0 : rs + 1;
    // kt = 31
    asm volatile("s_waitcnt vmcnt(0)" ::: "memory");
    __builtin_amdgcn_sched_barrier(0);
    asm volatile("s_barrier" ::: "memory");
    __builtin_amdgcn_sched_barrier(0);
    COMPUTE(rs);

    // ---- epilogue via LDS transpose (tbuf aliases the pipeline sets) -------
    // C/D map: col = lane&15, row = (lane>>4)*4 + reg
    const int col = lane & 15, rbase = (lane >> 4) * 4;
    __syncthreads();   // all frag reads done before tbuf overwrites sets
    if (z == 2) {
        // V: tbuf [d 0..127][tok 0..127], row stride 136 shorts.
        // Key-granule permutation: swap bits 2,3 of the token index (granule
        // pos within each 16-key group) -> PV B-frag is one b128 in attn.
#pragma unroll
        for (int tm = 0; tm < 4; ++tm)
#pragma unroll
            for (int tn = 0; tn < 4; ++tn) {
                const int dr = wn + tn * 16 + col;          // 0..127
                const float bs = bias[nz * 128 + dr];
                const int mi0 = wm + tm * 16 + rbase;       // 0..127, mult of 4
                const int mip = (mi0 & ~12) | ((mi0 & 4) << 1) | ((mi0 & 8) >> 1);
                unsigned short vals[4];
#pragma unroll
                for (int r = 0; r < 4; ++r) vals[r] = f2bf(acc[tm][tn][r] + bs);
                *(ushort4*)&tbuf[dr * 136 + mip] = *(ushort4*)vals;
            }
        __syncthreads();
        // writeback: each thread one 128 B contiguous chunk of a Vt d-row
        const int dr = tid >> 1, seg = tid & 1;
        const int hh = nz * 2 + (dr >> 6), dd = dr & 63;
        const int bb = m0 >> 11, tb = (m0 & (SEQ - 1)) >> 7;
        unsigned short* dst = O2 + (((size_t)bb * HEADS + hh) * HEAD_DIM + dd) * SEQ
                                 + tb * 128 + seg * 64;
        const unsigned short* srcl = &tbuf[dr * 136 + seg * 64];
#pragma unroll
        for (int i = 0; i < 8; ++i)
            *(uint4*)(dst + i * 8) = *(const uint4*)(srcl + i * 8);
    } else {
        unsigned short* O = (z == 0) ? O0 : O1;
        const float sc = (z == 0) ? SCALE_Q : 1.0f;
        // Q/K: tbuf [tok 0..127][n 0..127], row stride 136 shorts
#pragma unroll
        for (int tm = 0; tm < 4; ++tm)
#pragma unroll
            for (int tn = 0; tn < 4; ++tn) {
                const int nn = wn + tn * 16 + col;          // 0..127
                const float bs = bias[nz * 128 + nn];
                const int mi0 = wm + tm * 16 + rbase;
#pragma unroll
                for (int r = 0; r < 4; ++r)
                    tbuf[(mi0 + r) * 136 + nn] = f2bf((acc[tm][tn][r] + bs) * sc);
            }
        __syncthreads();
        // writeback: each thread one 128 B contiguous chunk of a token row
        const int r = tid >> 1, seg = tid & 1;
        unsigned short* dst = O + (size_t)(m0 + r) * HIDDEN + nz * 128 + seg * 64;
        const unsigned short* srcl = &tbuf[r * 136 + seg * 64];
#pragma unroll
        for (int i = 0; i < 8; ++i)
            *(uint4*)(dst + i * 8) = *(const uint4*)(srcl + i * 8);
    }
}

// ---- MFMA flash attention: 128 q/block, 2 waves, 64-key dbuf, 4 blk/CU -----
// grid 1024 (= 64 bh x 16 qc). XCD swizzle: all 16 q-chunks of one (b,h) on
// one XCD. TWO q-groups of 32 per wave (64 q/wave): K/V LDS frags read ONCE
// feed BOTH groups (16 ds_read : 32 MFMA per wave-iter). 2-wave blocks give
// 4 INDEPENDENT blocks/CU. r10 tweak: BOTH s32 sub-tiles' K-fragments are
// ds_read back-to-back right after the barrier (8 x b128) so s32=1's read
// latency hides under s32=0's QK/exp/PV compute (+16 VGPR, cap 256 at
// 2 waves/SIMD -> no spill).
// l accumulated on the VALU; epilogue redistributes per-query-row via shfl.
__global__ __launch_bounds__(128, 2) void attn_mfma(
    const unsigned short* __restrict__ Q, const unsigned short* __restrict__ K,
    const unsigned short* __restrict__ Vt, float* __restrict__ accp) {
    __shared__ unsigned short Klds[2][4096];  // 64 keys x 64 d, chunk-swizzled
    __shared__ unsigned short Vlds[2][4096];  // 64 d x 64 keys (perm), swizzled

    const int tid = threadIdx.x, lane = tid & 63, wave = tid >> 6;  // wave 0..1
    const int lq = lane & 31, g2 = lane >> 5;

    const int f = blockIdx.x;                 // 1024 = 64 bh x 16 qc
    const int bh = (f & 7) * 8 + ((f >> 3) & 7);
    const int qc = f >> 6;                    // 0..15 (128-q chunk)
    const int b = bh >> 4, h = bh & 15;

    // Q B-fragments: 2 groups of 32 q per wave, 4 k-slices each
    bf16x8 qfrag[2][4];
#pragma unroll
    for (int grp = 0; grp < 2; ++grp) {
        const size_t qb = ((size_t)(b * SEQ + qc * 128 + wave * 64 + grp * 32 + lq)) * HIDDEN
                          + h * HEAD_DIM + g2 * 8;
#pragma unroll
        for (int ds = 0; ds < 4; ++ds) qfrag[grp][ds] = *(const bf16x8*)&Q[qb + ds * 16];
    }

    // staging pointers. K: wave w covers rows [32w,32w+32) (4 instr x 8 rows);
    // V: d-rows [32w,32w+32). XOR chunk swizzle baked into the GLOBAL address
    // so lane-linear LDS writes give the swizzled layout.
    const unsigned short* kg[4];
    const unsigned short* vg[4];
    {
        const int kr = lane >> 3;                       // 0..7
        const int kc = ((lane & 7) ^ kr) * 8;
#pragma unroll
        for (int j = 0; j < 4; ++j)
            kg[j] = K + ((size_t)(b * SEQ + wave * 32 + j * 8 + kr)) * HIDDEN + h * HEAD_DIM + kc;
#pragma unroll
        for (int j = 0; j < 4; ++j) {
            const int dl = wave * 32 + j * 8 + (lane >> 3);
            const int cc = ((lane & 7) ^ (dl & 7)) * 8;
            vg[j] = Vt + ((size_t)bh * HEAD_DIM + dl) * SEQ + cc;
        }
    }

    floatx16 oacc[2][2];                      // [grp][nf]
#pragma unroll
    for (int r = 0; r < 16; ++r) {
        oacc[0][0][r] = 0.f; oacc[0][1][r] = 0.f;
        oacc[1][0][r] = 0.f; oacc[1][1][r] = 0.f;
    }
    // softmax denominator partials per group (two chains each)
    float lsum00 = 0.f, lsum01 = 0.f, lsum10 = 0.f, lsum11 = 0.f;

    // prologue: stage tile 0 into buf 0
#pragma unroll
    for (int j = 0; j < 4; ++j) {
        async_cp16(kg[j], (char*)Klds[0] + (wave * 32 + j * 8) * 128);
        async_cp16(vg[j], (char*)Vlds[0] + (wave * 32 + j * 8) * 128);
        kg[j] += 64 * HIDDEN; vg[j] += 64;
    }
    __syncthreads();

    for (int it = 0; it < 32; ++it) {
        const int cur = it & 1;
        if (it < 31) {
#pragma unroll
            for (int j = 0; j < 4; ++j) {
                async_cp16(kg[j], (char*)Klds[cur ^ 1] + (wave * 32 + j * 8) * 128);
                async_cp16(vg[j], (char*)Vlds[cur ^ 1] + (wave * 32 + j * 8) * 128);
                kg[j] += 64 * HIDDEN; vg[j] += 64;
            }
        }
        // --- hoisted K-fragment reads for BOTH 32-key sub-tiles -------------
        bf16x8 kfa[2][4];
#pragma unroll
        for (int s32 = 0; s32 < 2; ++s32)
#pragma unroll
            for (int ds = 0; ds < 4; ++ds)
                kfa[s32][ds] = *(bf16x8*)((char*)Klds[cur] + (s32 * 32 + lq) * 128
                                          + (((g2 + 2 * ds) ^ (lq & 7)) * 16));
#pragma unroll
        for (int s32 = 0; s32 < 2; ++s32) {
            // --- all QK^T MFMAs first (two independent chains) ---
            floatx16 sacc0, sacc1;
#pragma unroll
            for (int r = 0; r < 16; ++r) { sacc0[r] = 0.f; sacc1[r] = 0.f; }
#pragma unroll
            for (int ds = 0; ds < 4; ++ds)
                sacc0 = __builtin_amdgcn_mfma_f32_32x32x16_bf16(kfa[s32][ds], qfrag[0][ds], sacc0, 0, 0, 0);
#pragma unroll
            for (int ds = 0; ds < 4; ++ds)
                sacc1 = __builtin_amdgcn_mfma_f32_32x32x16_bf16(kfa[s32][ds], qfrag[1][ds], sacc1, 0, 0, 0);

            // --- V-frag ds_reads issued early: latency hides under exp2 ---
            bf16x8 vf[2][2];                 // [ks2][nf]
#pragma unroll
            for (int ks2 = 0; ks2 < 2; ++ks2)
#pragma unroll
                for (int nf = 0; nf < 2; ++nf) {
                    const int d = nf * 32 + lq;
                    const int c = (2 * (s32 * 2 + ks2) + g2) ^ (d & 7);
                    vf[ks2][nf] = *(bf16x8*)((char*)Vlds[cur] + d * 128 + c * 16);
                }

            // --- softmax exp/pack for both groups (overlaps QK execution) ---
            unsigned pk[2][8];
#pragma unroll
            for (int j = 0; j < 8; ++j) {
                union { float f; unsigned u; } plo, phi;
                plo.f = fast_exp2(sacc0[2 * j]);
                phi.f = fast_exp2(sacc0[2 * j + 1]);
                lsum00 += plo.f; lsum01 += phi.f;
                pk[0][j] = __builtin_amdgcn_perm(phi.u, plo.u, 0x07060302u);
            }
#pragma unroll
            for (int j = 0; j < 8; ++j) {
                union { float f; unsigned u; } plo, phi;
                plo.f = fast_exp2(sacc1[2 * j]);
                phi.f = fast_exp2(sacc1[2 * j + 1]);
                lsum10 += plo.f; lsum11 += phi.f;
                pk[1][j] = __builtin_amdgcn_perm(phi.u, plo.u, 0x07060302u);
            }

            // --- all PV MFMAs ---
#pragma unroll
            for (int ks2 = 0; ks2 < 2; ++ks2)
#pragma unroll
                for (int grp = 0; grp < 2; ++grp) {
                    union { uint4 u; bf16x8 v; } af;
                    af.u.x = pk[grp][4 * ks2];
                    af.u.y = pk[grp][4 * ks2 + 1];
                    af.u.z = pk[grp][4 * ks2 + 2];
                    af.u.w = pk[grp][4 * ks2 + 3];
#pragma unroll
                    for (int nf = 0; nf < 2; ++nf)
                        oacc[grp][nf] = __builtin_amdgcn_mfma_f32_32x32x16_bf16(af.v, vf[ks2][nf], oacc[grp][nf], 0, 0, 0);
                }
        }
        if (it < 31) __syncthreads();
    }

    // epilogue: per group, combine l partials (per query column lq) across the
    // two g2 halves, then redistribute to this lane's 16 oacc query ROWS:
    // q_r = (r&3) + 8*(r>>2) + 4*g2 ; l[q] lives in lanes q and q+32.
    float linv[2][16];
#pragma unroll
    for (int grp = 0; grp < 2; ++grp) {
        float lf = (grp == 0) ? (lsum00 + lsum01) : (lsum10 + lsum11);
        lf += __shfl_xor(lf, 32, 64);
#pragma unroll
        for (int r = 0; r < 16; ++r) {
            const int qr = (r & 3) + 8 * (r >> 2) + 4 * g2;
            linv[grp][r] = 1.0f / __shfl(lf, qr, 64);
        }
    }
    // d-col = lane&31 (+32*nf); sum_q o[q][d]/l[q] over the wave's 64 rows
#pragma unroll
    for (int nf = 0; nf < 2; ++nf) {
        float v = 0.f;
#pragma unroll
        for (int r = 0; r < 16; ++r)
            v += oacc[0][nf][r] * linv[0][r] + oacc[1][nf][r] * linv[1][r];
        v += __shfl_xor(v, 32, 64);
        if (lane < 32)
            atomicAdd(&accp[b * HIDDEN + h * HEAD_DIM + nf * 32 + lq], v);
    }
}

// ---- final projection: out = (acc/T) @ Wo^T + bo ---------------------------
// grid 256: block bi covers n = 4*bi..4*bi+3, ALL 4 batches (full-chip).
// 64 lanes per n, each lane 16 k-elements; wave shuffle-reduce; lanes 0-3
// write the 4 batch outputs.
__global__ __launch_bounds__(256) void out_proj(const float* __restrict__ acc,
                                                const float* __restrict__ Wo,
                                                const float* __restrict__ bo,
                                                float* __restrict__ out) {
    const int tid = threadIdx.x;
    const int nl = tid >> 6, lane = tid & 63;
    const int n = blockIdx.x * 4 + nl;
    const float* wr = Wo + (size_t)n * HIDDEN + lane * 16;
    float s0 = 0.f, s1 = 0.f, s2 = 0.f, s3 = 0.f;
#pragma unroll
    for (int kk = 0; kk < 4; ++kk) {
        float4 w = *(const float4*)(wr + kk * 4);
        float4 a0 = *(const float4*)(acc + 0 * HIDDEN + lane * 16 + kk * 4);
        float4 a1 = *(const float4*)(acc + 1 * HIDDEN + lane * 16 + kk * 4);
        float4 a2 = *(const float4*)(acc + 2 * HIDDEN + lane * 16 + kk * 4);
        float4 a3 = *(const float4*)(acc + 3 * HIDDEN + lane * 16 + kk * 4);
        s0 += w.x * a0.x + w.y * a0.y + w.z * a0.z + w.w * a0.w;
        s1 += w.x * a1.x + w.y * a1.y + w.z * a1.z + w.w * a1.w;
        s2 += w.x * a2.x + w.y * a2.y + w.z * a2.z + w.w * a2.w;
        s3 += w.x * a3.x + w.y * a3.y + w.z * a3.z + w.w * a3.w;
    }
#pragma unroll
    for (int off = 32; off; off >>= 1) {
        s0 += __shfl_xor(s0, off, 64);
        s1 += __shfl_xor(s1, off, 64);
        s2 += __shfl_xor(s2, off, 64);
        s3 += __shfl_xor(s3, off, 64);
    }
    if (lane < 4) {
        float sv = (lane == 0) ? s0 : (lane == 1) ? s1 : (lane == 2) ? s2 : s3;
        out[lane * HIDDEN + n] = sv * (1.0f / (float)SEQ) + bo[n];
    }
}

extern "C" void kernel_launch(void* const* d_in, const int* in_sizes, int n_in,
                              void* d_out, int out_size, void* d_ws, size_t ws_size,
                              hipStream_t stream) {
    const float* x  = (const float*)d_in[0];
    const float* Wq = (const float*)d_in[1];
    const float* bq = (const float*)d_in[2];
    const float* Wk = (const float*)d_in[3];
    const float* bk = (const float*)d_in[4];
    const float* Wv = (const float*)d_in[5];
    const float* bv = (const float*)d_in[6];
    const float* Wo = (const float*)d_in[7];
    const float* bo = (const float*)d_in[8];
    float* out = (float*)d_out;

    char* ws = (char*)d_ws;
    unsigned short* x_bf  = (unsigned short*)(ws);                      // 16 MB
    unsigned short* wq_bf = (unsigned short*)(ws + 16777216);           //  2 MB
    unsigned short* wk_bf = (unsigned short*)(ws + 18874368);           //  2 MB
    unsigned short* wv_bf = (unsigned short*)(ws + 20971520);           //  2 MB
    unsigned short* q_bf  = (unsigned short*)(ws + 23068672);           // 16 MB (pre-scaled Q)
    unsigned short* k_bf  = (unsigned short*)(ws + 39845888);           // 16 MB
    unsigned short* vt_bf = (unsigned short*)(ws + 56623104);           // 16 MB (V^T, granule-perm)
    float*          accp  = (float*)(ws + 73400320);                    // 16 KB

    conv_all<<<dim3(8192 + 3072), dim3(256), 0, stream>>>(
        x, Wq, Wk, Wv, x_bf, wq_bf, wk_bf, wv_bf, accp);

    qkv_gemm<<<dim3(1536), dim3(256), 0, stream>>>(
        x_bf, wq_bf, wk_bf, wv_bf, bq, bk, bv, q_bf, k_bf, vt_bf);

    attn_mfma<<<dim3(1024), dim3(128), 0, stream>>>(q_bf, k_bf, vt_bf, accp);

    out_proj<<<dim3(256), dim3(256), 0, stream>>>(accp, Wo, bo, out);
}